// Round 1
// baseline (98.199 us; speedup 1.0000x reference)
//
#include <hip/hip_runtime.h>
#include <hip/hip_bf16.h>

// Problem constants (fixed by setup_inputs)
#define NPROT 150
#define KPROT 32
#define CDIM  512
#define BDIM  8
#define HWDIM 1024
#define MDIM  (NPROT * KPROT)   // 4800
#define PDIM  (BDIM * HWDIM)    // 8192

typedef short bf16x8 __attribute__((ext_vector_type(8)));
typedef float f32x4  __attribute__((ext_vector_type(4)));

__device__ __forceinline__ unsigned short f2bf(float x) {
  unsigned int u = __float_as_uint(x);
  u = u + 0x7fffu + ((u >> 16) & 1u);   // round-to-nearest-even
  return (unsigned short)(u >> 16);
}
__device__ __forceinline__ float bf2f(unsigned short s) {
  return __uint_as_float(((unsigned int)s) << 16);
}

// ---------- kernel 1: proto l2-norm -> Abf[m][c] bf16 (one wave per row) ----------
__global__ __launch_bounds__(256) void proto_norm_k(const float* __restrict__ proto,
                                                    unsigned short* __restrict__ Abf) {
  int gid  = blockIdx.x * 256 + threadIdx.x;
  int row  = gid >> 6;
  int lane = gid & 63;
  if (row >= MDIM) return;
  const float4* rp = (const float4*)(proto + (size_t)row * CDIM);
  float4 v0 = rp[lane * 2];
  float4 v1 = rp[lane * 2 + 1];
  float ss = v0.x*v0.x + v0.y*v0.y + v0.z*v0.z + v0.w*v0.w
           + v1.x*v1.x + v1.y*v1.y + v1.z*v1.z + v1.w*v1.w;
  #pragma unroll
  for (int o = 32; o > 0; o >>= 1) ss += __shfl_xor(ss, o, 64);
  float inv = rsqrtf(ss + 1e-12f);
  __align__(16) unsigned short o8[8];
  o8[0]=f2bf(v0.x*inv); o8[1]=f2bf(v0.y*inv); o8[2]=f2bf(v0.z*inv); o8[3]=f2bf(v0.w*inv);
  o8[4]=f2bf(v1.x*inv); o8[5]=f2bf(v1.y*inv); o8[6]=f2bf(v1.z*inv); o8[7]=f2bf(v1.w*inv);
  *(int4*)(Abf + (size_t)row * CDIM + lane * 8) = *(const int4*)o8;
}

// ---------- kernel 2: image inv-norm + transpose -> Bbf[p][c] bf16 ----------
// block = 256 threads handles 32 pixels (one b, 32 consecutive hw), all 512 c.
__global__ __launch_bounds__(256) void img_prep_k(const float* __restrict__ img,
                                                  unsigned short* __restrict__ Bbf) {
  __shared__ unsigned short tile[32][520];  // +8 pad to break bank cycle
  __shared__ float partial[8][32];
  __shared__ float invn[32];
  int t   = threadIdx.x;
  int bid = blockIdx.x;          // 256 blocks
  int b   = bid >> 5;
  int hw0 = (bid & 31) << 5;
  int hwo = t & 31;
  int cg  = t >> 5;              // 0..7
  const float* base = img + ((size_t)b << 19) + hw0 + hwo;  // b*512*1024
  float ss = 0.f;
  #pragma unroll 8
  for (int i = 0; i < 64; ++i) {
    int c = i * 8 + cg;
    float v = base[(size_t)c << 10];
    ss += v * v;
    tile[hwo][c] = f2bf(v);
  }
  partial[cg][hwo] = ss;
  __syncthreads();
  if (t < 32) {
    float s = 0.f;
    #pragma unroll
    for (int j = 0; j < 8; ++j) s += partial[j][t];
    invn[t] = rsqrtf(s + 1e-12f);
  }
  __syncthreads();
  int r  = t >> 3;               // 0..31 pixel row
  int c0 = (t & 7) * 64;         // 0..448
  float sc = invn[r];
  unsigned short* dst = Bbf + ((((size_t)b << 10) + hw0 + r)) * CDIM + c0;
  #pragma unroll
  for (int j = 0; j < 8; ++j) {
    __align__(16) unsigned short o8[8];
    #pragma unroll
    for (int e = 0; e < 8; ++e) o8[e] = f2bf(bf2f(tile[r][c0 + j*8 + e]) * sc);
    *(int4*)(dst + j*8) = *(const int4*)o8;
  }
}

// ---------- kernel 3: S = A·B^T tile + fused k-reduction epilogue ----------
// tile: BM=64 (2 n-groups) x BP=128 pixels, BK=64 staged. 4 waves (2m x 2p),
// each wave 32x64 via 2x4 fragments of mfma_f32_16x16x32_bf16.
#define LDA 72    // padded LDS stride (bf16 elems): 144B = 36 words = 4 mod 32 banks
#define LDSS 132  // epilogue fp32 stride
__global__ __launch_bounds__(256) void gemm_k(const unsigned short* __restrict__ Abf,
                                              const unsigned short* __restrict__ Bbf,
                                              float* __restrict__ out) {
  __shared__ __align__(16) char smem[64 * LDSS * 4];  // 33792 B, unioned
  unsigned short* As = (unsigned short*)smem;          // [64][72]
  unsigned short* Bs = As + 64 * LDA;                  // [128][72]
  float* S = (float*)smem;                             // [64][132]

  int t    = threadIdx.x;
  int lane = t & 63;
  int wid  = t >> 6;
  int wm   = wid >> 1, wp = wid & 1;
  int m0 = blockIdx.y * 64;
  int p0 = blockIdx.x * 128;
  int lr = lane & 15;
  int lg = lane >> 4;

  f32x4 acc[2][4];
  #pragma unroll
  for (int i = 0; i < 2; ++i)
    #pragma unroll
    for (int j = 0; j < 4; ++j) acc[i][j] = (f32x4)(0.f);

  const int4* Ag = (const int4*)(Abf + (size_t)m0 * CDIM);
  const int4* Bg = (const int4*)(Bbf + (size_t)p0 * CDIM);

  for (int c0 = 0; c0 < CDIM; c0 += 64) {
    int cb = c0 >> 3;  // int4 index offset within a row
    #pragma unroll
    for (int it = 0; it < 2; ++it) {        // A: 64 rows x 64c = 512 chunks
      int idx = it * 256 + t;
      int row = idx >> 3, c8 = idx & 7;
      int4 v = Ag[row * (CDIM / 8) + cb + c8];
      *(int4*)(As + row * LDA + c8 * 8) = v;
    }
    #pragma unroll
    for (int it = 0; it < 4; ++it) {        // B: 128 rows = 1024 chunks
      int idx = it * 256 + t;
      int row = idx >> 3, c8 = idx & 7;
      int4 v = Bg[row * (CDIM / 8) + cb + c8];
      *(int4*)(Bs + row * LDA + c8 * 8) = v;
    }
    __syncthreads();
    #pragma unroll
    for (int kk = 0; kk < 2; ++kk) {
      int koff = kk * 32 + lg * 8;
      bf16x8 af[2], bfr[4];
      #pragma unroll
      for (int fm = 0; fm < 2; ++fm)
        af[fm] = *(const bf16x8*)(As + (wm * 32 + fm * 16 + lr) * LDA + koff);
      #pragma unroll
      for (int fp = 0; fp < 4; ++fp)
        bfr[fp] = *(const bf16x8*)(Bs + (wp * 64 + fp * 16 + lr) * LDA + koff);
      #pragma unroll
      for (int fm = 0; fm < 2; ++fm)
        #pragma unroll
        for (int fp = 0; fp < 4; ++fp)
          acc[fm][fp] = __builtin_amdgcn_mfma_f32_16x16x32_bf16(af[fm], bfr[fp], acc[fm][fp], 0, 0, 0);
    }
    __syncthreads();
  }

  // spill S tile to LDS: D row=(lane>>4)*4+reg, col=lane&15 (verified layout)
  #pragma unroll
  for (int fm = 0; fm < 2; ++fm)
    #pragma unroll
    for (int fp = 0; fp < 4; ++fp)
      #pragma unroll
      for (int r = 0; r < 4; ++r) {
        int ml = wm * 32 + fm * 16 + lg * 4 + r;
        int pl = wp * 64 + fp * 16 + lr;
        S[ml * LDSS + pl] = acc[fm][fp][r];
      }
  __syncthreads();

  // reduce over k=32 rows per n-group; 256 threads = 2 groups x 128 cols
  int g = t >> 7;
  int col = t & 127;
  float mx = -1e30f, sm = 0.f;
  #pragma unroll 8
  for (int r = 0; r < 32; ++r) {
    float v = S[(g * 32 + r) * LDSS + col];
    mx = fmaxf(mx, v);
    sm += v;
  }
  float sim  = 0.5f * mx + sm * (0.5f / 32.0f);
  float mask = 1.0f / (1.0f + __expf(-sim));
  int n = blockIdx.y * 2 + g;
  int p = p0 + col;
  int b = p >> 10, hw = p & 1023;
  size_t o = ((size_t)(b * NPROT + n) << 10) + hw;
  out[o] = mask;
  out[(size_t)BDIM * NPROT * HWDIM + o] = sim;
}

extern "C" void kernel_launch(void* const* d_in, const int* in_sizes, int n_in,
                              void* d_out, int out_size, void* d_ws, size_t ws_size,
                              hipStream_t stream) {
  const float* img   = (const float*)d_in[0];   // [8,512,32,32]
  const float* proto = (const float*)d_in[1];   // [150,32,512]
  float* out = (float*)d_out;                   // soft_mask | sim, fp32
  unsigned short* Abf = (unsigned short*)d_ws;                 // 4800*512 bf16
  unsigned short* Bbf = Abf + (size_t)MDIM * CDIM;             // 8192*512 bf16
  // ws requirement: (4800+8192)*512*2 = 13,303,808 bytes

  proto_norm_k<<<MDIM / 4, 256, 0, stream>>>(proto, Abf);          // 1200 blocks
  img_prep_k<<<BDIM * 32, 256, 0, stream>>>(img, Bbf);             // 256 blocks
  gemm_k<<<dim3(PDIM / 128, MDIM / 64), 256, 0, stream>>>(Abf, Bbf, out);  // 64x75
}

// Round 2
// 62.512 us; speedup vs baseline: 1.5709x; 1.5709x over previous
//
#include <hip/hip_runtime.h>
#include <hip/hip_bf16.h>

// Problem constants (fixed by setup_inputs)
#define NPROT 150
#define KPROT 32
#define CDIM  512
#define BDIM  8
#define HWDIM 1024
#define MDIM  (NPROT * KPROT)   // 4800
#define PDIM  (BDIM * HWDIM)    // 8192

typedef short bf16x8 __attribute__((ext_vector_type(8)));
typedef float f32x4  __attribute__((ext_vector_type(4)));

__device__ __forceinline__ unsigned short f2bf(float x) {
  unsigned int u = __float_as_uint(x);
  u = u + 0x7fffu + ((u >> 16) & 1u);   // round-to-nearest-even
  return (unsigned short)(u >> 16);
}
__device__ __forceinline__ float bf2f(unsigned short s) {
  return __uint_as_float(((unsigned int)s) << 16);
}

// async global->LDS, 16B per lane; LDS dest must be linear (base + lane*16)
#define GLOAD_LDS16(gsrc, ldst) __builtin_amdgcn_global_load_lds(            \
    (const __attribute__((address_space(1))) void*)(gsrc),                   \
    (__attribute__((address_space(3))) void*)(ldst), 16, 0, 0)

// ---------- kernel 1 (fused preps): blocks 0..255 = image prep, 256..1455 = proto norm ----
__global__ __launch_bounds__(256) void prep_k(const float* __restrict__ img,
                                              const float* __restrict__ proto,
                                              unsigned short* __restrict__ Abf,
                                              unsigned short* __restrict__ Bbf) {
  __shared__ unsigned short tile[32][520];
  __shared__ float partial[8][32];
  __shared__ float invn[32];
  int t   = threadIdx.x;
  int bid = blockIdx.x;
  if (bid >= 256) {
    // ---- proto l2-norm: one wave per row, 4 rows/block ----
    int row  = (bid - 256) * 4 + (t >> 6);
    int lane = t & 63;
    const float4* rp = (const float4*)(proto + (size_t)row * CDIM);
    float4 v0 = rp[lane * 2];
    float4 v1 = rp[lane * 2 + 1];
    float ss = v0.x*v0.x + v0.y*v0.y + v0.z*v0.z + v0.w*v0.w
             + v1.x*v1.x + v1.y*v1.y + v1.z*v1.z + v1.w*v1.w;
    #pragma unroll
    for (int o = 32; o > 0; o >>= 1) ss += __shfl_xor(ss, o, 64);
    float inv = rsqrtf(ss + 1e-12f);
    __align__(16) unsigned short o8[8];
    o8[0]=f2bf(v0.x*inv); o8[1]=f2bf(v0.y*inv); o8[2]=f2bf(v0.z*inv); o8[3]=f2bf(v0.w*inv);
    o8[4]=f2bf(v1.x*inv); o8[5]=f2bf(v1.y*inv); o8[6]=f2bf(v1.z*inv); o8[7]=f2bf(v1.w*inv);
    *(int4*)(Abf + (size_t)row * CDIM + lane * 8) = *(const int4*)o8;
    return;
  }
  // ---- image inv-norm + transpose: 32 pixels/block, all 512 c ----
  int b   = bid >> 5;
  int hw0 = (bid & 31) << 5;
  int hwo = t & 31;
  int cg  = t >> 5;              // 0..7
  const float* base = img + ((size_t)b << 19) + hw0 + hwo;  // b*512*1024
  float ss = 0.f;
  #pragma unroll 8
  for (int i = 0; i < 64; ++i) {
    int c = i * 8 + cg;
    float v = base[(size_t)c << 10];
    ss += v * v;
    tile[hwo][c] = f2bf(v);
  }
  partial[cg][hwo] = ss;
  __syncthreads();
  if (t < 32) {
    float s = 0.f;
    #pragma unroll
    for (int j = 0; j < 8; ++j) s += partial[j][t];
    invn[t] = rsqrtf(s + 1e-12f);
  }
  __syncthreads();
  int r  = t >> 3;
  int c0 = (t & 7) * 64;
  float sc = invn[r];
  unsigned short* dst = Bbf + ((((size_t)b << 10) + hw0 + r)) * CDIM + c0;
  #pragma unroll
  for (int j = 0; j < 8; ++j) {
    __align__(16) unsigned short o8[8];
    #pragma unroll
    for (int e = 0; e < 8; ++e) o8[e] = f2bf(bf2f(tile[r][c0 + j*8 + e]) * sc);
    *(int4*)(dst + j*8) = *(const int4*)o8;
  }
}

// ---------- kernel 2: S = A·B^T, 64x256 tile, BK=64, global_load_lds staging ----------
// 4 waves (1m x 4p), each wave 64 rows x 64 cols via 4x4 frags of 16x16x32.
// LDS linear; XOR granule swizzle (g ^= row&7) applied on the GLOBAL source and
// undone on the ds_read address (both-sides involution, rule #21).
__global__ __launch_bounds__(256, 3) void gemm_k(const unsigned short* __restrict__ Abf,
                                                 const unsigned short* __restrict__ Bbf,
                                                 float* __restrict__ out) {
  __shared__ __align__(16) unsigned short smem[(64 + 256) * 64];  // A 8KB | B 32KB
  unsigned short* As = smem;
  unsigned short* Bs = smem + 64 * 64;

  int t    = threadIdx.x;
  int lane = t & 63;
  int w    = t >> 6;             // wave id = p-quadrant
  int lr   = lane & 15;
  int lg   = lane >> 4;
  int m0   = blockIdx.y * 64;    // 75 blocks, exact
  int p0   = blockIdx.x * 256;   // 32 blocks, exact

  f32x4 acc[4][4] = {};

  const char* Ab = (const char*)(Abf + (size_t)m0 * CDIM);
  const char* Bb = (const char*)(Bbf + (size_t)p0 * CDIM);

  for (int c0 = 0; c0 < CDIM; c0 += 64) {
    int cb = c0 * 2;                       // byte offset of K-slice within a row
    // stage A: 64 rows x 128B = 512 granules of 16B
    #pragma unroll
    for (int it = 0; it < 2; ++it) {
      int gi  = it * 256 + t;
      int row = gi >> 3, g = gi & 7;
      int gs  = g ^ (row & 7);             // pre-swizzled source granule
      GLOAD_LDS16(Ab + (size_t)row * 1024 + cb + gs * 16, (char*)As + gi * 16);
    }
    // stage B: 256 rows = 2048 granules
    #pragma unroll
    for (int it = 0; it < 8; ++it) {
      int gi  = it * 256 + t;
      int row = gi >> 3, g = gi & 7;
      int gs  = g ^ (row & 7);
      GLOAD_LDS16(Bb + (size_t)row * 1024 + cb + gs * 16, (char*)Bs + gi * 16);
    }
    __syncthreads();   // compiler emits vmcnt(0) drain before barrier

    #pragma unroll
    for (int kk = 0; kk < 2; ++kk) {
      int gbase = kk * 4 + lg;             // wanted global granule index
      bf16x8 af[4], bfr[4];
      #pragma unroll
      for (int fm = 0; fm < 4; ++fm) {
        int row = fm * 16 + lr;
        af[fm] = *(const bf16x8*)((const char*)As + row * 128 + (gbase ^ (row & 7)) * 16);
      }
      #pragma unroll
      for (int fp = 0; fp < 4; ++fp) {
        int row = w * 64 + fp * 16 + lr;
        bfr[fp] = *(const bf16x8*)((const char*)Bs + row * 128 + (gbase ^ (row & 7)) * 16);
      }
      #pragma unroll
      for (int fm = 0; fm < 4; ++fm)
        #pragma unroll
        for (int fp = 0; fp < 4; ++fp)
          acc[fm][fp] = __builtin_amdgcn_mfma_f32_16x16x32_bf16(af[fm], bfr[fp], acc[fm][fp], 0, 0, 0);
    }
    __syncthreads();
  }

  // ---- fused epilogue, fully in-register ----
  // acc[fm][fp][r] = S[m][p], m = fm*16 + lg*4 + r, p = p0 + w*64 + fp*16 + lr.
  // n-group = m>>5 -> frags {0,1} = group 0, {2,3} = group 1 (each wave: 2 groups).
  #pragma unroll
  for (int gi = 0; gi < 2; ++gi) {
    #pragma unroll
    for (int fp = 0; fp < 4; ++fp) {
      float mx = -1e30f, sm = 0.f;
      #pragma unroll
      for (int fm = 2 * gi; fm < 2 * gi + 2; ++fm)
        #pragma unroll
        for (int r = 0; r < 4; ++r) {
          float v = acc[fm][fp][r];
          mx = fmaxf(mx, v);
          sm += v;
        }
      mx = fmaxf(mx, __shfl_xor(mx, 16, 64));
      mx = fmaxf(mx, __shfl_xor(mx, 32, 64));
      sm += __shfl_xor(sm, 16, 64);
      sm += __shfl_xor(sm, 32, 64);
      if (lg == 0) {
        float sim  = 0.5f * mx + sm * (0.5f / 32.0f);
        float mask = 1.0f / (1.0f + __expf(-sim));
        int n  = blockIdx.y * 2 + gi;
        int p  = p0 + w * 64 + fp * 16 + lr;
        int b  = p >> 10, hw = p & 1023;
        size_t o = ((size_t)(b * NPROT + n) << 10) + hw;
        out[o] = mask;
        out[(size_t)(BDIM * NPROT * HWDIM) + o] = sim;
      }
    }
  }
}

extern "C" void kernel_launch(void* const* d_in, const int* in_sizes, int n_in,
                              void* d_out, int out_size, void* d_ws, size_t ws_size,
                              hipStream_t stream) {
  const float* img   = (const float*)d_in[0];   // [8,512,32,32]
  const float* proto = (const float*)d_in[1];   // [150,32,512]
  float* out = (float*)d_out;
  unsigned short* Abf = (unsigned short*)d_ws;                 // 4800*512 bf16
  unsigned short* Bbf = Abf + (size_t)MDIM * CDIM;             // 8192*512 bf16
  // ws requirement: (4800+8192)*512*2 = 13,303,808 bytes

  prep_k<<<256 + MDIM / 4, 256, 0, stream>>>(img, proto, Abf, Bbf);
  gemm_k<<<dim3(PDIM / 256, MDIM / 64), 256, 0, stream>>>(Abf, Bbf, out);
}